// Round 1
// 364.317 us; speedup vs baseline: 1.0002x; 1.0002x over previous
//
#include <hip/hip_runtime.h>

typedef unsigned short ushort_t;
typedef unsigned int   uint32;
typedef __attribute__((ext_vector_type(8)))  short short8;    // 8 x bf16 (4 VGPRs)
typedef __attribute__((ext_vector_type(4)))  float floatx4;
typedef __attribute__((ext_vector_type(16))) float floatx16;  // 32x32 MFMA accumulator

#define IN_F   4096
#define OUT_F  8192
#define M_TOT  512

__device__ __forceinline__ ushort_t f2bf(float f) {
    uint32 u = __builtin_bit_cast(uint32, f);
    u += 0x7FFFu + ((u >> 16) & 1u);    // RNE
    return (ushort_t)(u >> 16);
}
__device__ __forceinline__ uint32 pack2bf(float a, float b) {
    return (uint32)f2bf(a) | ((uint32)f2bf(b) << 16);
}

// ---------------------------------------------------------------------------
// Kernel 0: x fp32 -> bf16 into workspace (4 MB).
__global__ void cvt_x_kernel(const float* __restrict__ x, ushort_t* __restrict__ xb) {
    int i = (blockIdx.x * 256 + threadIdx.x) * 8;
    float4 v0 = *(const float4*)(x + i);
    float4 v1 = *(const float4*)(x + i + 4);
    short8 s;
    s[0] = (short)f2bf(v0.x); s[1] = (short)f2bf(v0.y);
    s[2] = (short)f2bf(v0.z); s[3] = (short)f2bf(v0.w);
    s[4] = (short)f2bf(v1.x); s[5] = (short)f2bf(v1.y);
    s[6] = (short)f2bf(v1.z); s[7] = (short)f2bf(v1.w);
    *(short8*)(xb + i) = s;
}

// ---------------------------------------------------------------------------
// Kernel 1: dequant W -> bf16 [OUT_F][IN_F].
// Round 6 rewrite: counters showed 105 us vs 53 us HBM floor with VALUBusy 5%,
// occupancy 37%, conflicts <5% -> latency-bound, not throughput-bound.
// Changes: (a) grid 512 -> 256 blocks (exactly 1/CU; ONE block round, LUT
// staged once instead of twice); (b) each block owns 32 rows x full 4096 cols;
// (c) depth-4 cyclic register prefetch, fully unrolled (static indices), 8
// ints/lane/step -> 16 outstanding 16B loads/thread (~256 KB/CU in flight);
// (d) 16B uint4 stores.  __launch_bounds__(1024,4) caps VGPR at 128 so all
// 16 waves stay resident.
__global__ __launch_bounds__(1024, 4)
void dequant_kernel(const int* __restrict__ base_idx, const int* __restrict__ fine_idx,
                    const float* __restrict__ lut, ushort_t* __restrict__ wq)
{
    __shared__ ushort_t sh_lut[65536];   // 128 KB bf16 LUT
    const int tid = threadIdx.x;
#pragma unroll
    for (int i = tid * 4; i < 65536; i += 1024 * 4) {
        float4 v = *(const float4*)(lut + i);
        *(uint32*)&sh_lut[i]     = pack2bf(v.x, v.y);
        *(uint32*)&sh_lut[i + 2] = pack2bf(v.z, v.w);
    }

    const int row = blockIdx.x * 32 + (tid >> 5);
    const int c0  = (tid & 31) * 8;                    // 8 ints per lane per step
    const int* bp = base_idx + (size_t)row * IN_F + c0;
    const int* fp = fine_idx + (size_t)row * IN_F + c0;
    ushort_t*  op = wq       + (size_t)row * IN_F + c0;

    // Cyclic prefetch buffers: 4 steps deep, 2 int4 per source per step.
    int4 cb[4][2], cf[4][2];
#pragma unroll
    for (int d = 0; d < 4; ++d) {
        cb[d][0] = *(const int4*)(bp + d * 256);
        cb[d][1] = *(const int4*)(bp + d * 256 + 4);
        cf[d][0] = *(const int4*)(fp + d * 256);
        cf[d][1] = *(const int4*)(fp + d * 256 + 4);
    }
    __syncthreads();   // LUT ready (idx prefetch already in flight across it)

#pragma unroll
    for (int u = 0; u < 16; ++u) {        // 16 steps x 256 cols = 4096
        const int s = u & 3;
        const int4 b0 = cb[s][0], b1 = cb[s][1];
        const int4 f0 = cf[s][0], f1 = cf[s][1];
        if (u + 4 < 16) {
            cb[s][0] = *(const int4*)(bp + (u + 4) * 256);
            cb[s][1] = *(const int4*)(bp + (u + 4) * 256 + 4);
            cf[s][0] = *(const int4*)(fp + (u + 4) * 256);
            cf[s][1] = *(const int4*)(fp + (u + 4) * 256 + 4);
        }
        uint32 w0 = (uint32)sh_lut[(b0.x << 8) + f0.x]
                  | ((uint32)sh_lut[(b0.y << 8) + f0.y] << 16);
        uint32 w1 = (uint32)sh_lut[(b0.z << 8) + f0.z]
                  | ((uint32)sh_lut[(b0.w << 8) + f0.w] << 16);
        uint32 w2 = (uint32)sh_lut[(b1.x << 8) + f1.x]
                  | ((uint32)sh_lut[(b1.y << 8) + f1.y] << 16);
        uint32 w3 = (uint32)sh_lut[(b1.z << 8) + f1.z]
                  | ((uint32)sh_lut[(b1.w << 8) + f1.w] << 16);
        uint4 wv; wv.x = w0; wv.y = w1; wv.z = w2; wv.w = w3;
        *(uint4*)(op + u * 256) = wv;
    }
}

// ---------------------------------------------------------------------------
// Kernel 2: K-split GEMM partials.  part[z][512,8192] = xb[:, zK:(z+1)K] *
// wq[:, zK:(z+1)K]^T, z=0,1, K=2048.  Grid (4,64,2) = 512 blocks -> 2
// blocks/CU (64 KB LDS), 8 waves/CU: one block's compute hides the other's
// barrier drain (m114 overlap).
#define BK 128
__global__ __launch_bounds__(256, 2)
void gemm_split_kernel(const ushort_t* __restrict__ xb, const ushort_t* __restrict__ wq,
                       float* __restrict__ part)
{
    __shared__ ushort_t shA[128 * BK];   // 32 KB
    __shared__ ushort_t shB[128 * BK];   // 32 KB

    const int tid  = threadIdx.x;
    const int wave = tid >> 6;
    const int m0   = blockIdx.x * 128;
    const int n0   = blockIdx.y * 128;
    const int kz   = blockIdx.z * (IN_F / 2);   // 0 or 2048

    const int g = (tid & 15) ^ ((tid >> 4) & 7);
    const ushort_t* aBase = xb + (size_t)(m0 + (tid >> 4)) * IN_F + kz + g * 8;
    const ushort_t* bBase = wq + (size_t)(n0 + (tid >> 4)) * IN_F + kz + g * 8;
    typedef __attribute__((address_space(3))) ushort_t lds_us;
    typedef const __attribute__((address_space(1))) void gvoid;
    lds_us* sA3 = (lds_us*)shA;
    lds_us* sB3 = (lds_us*)shB;

    const int lane = tid & 63;
    const int l31  = lane & 31;
    const int lhi  = lane >> 5;
    const int qm   = wave & 1;
    const int qn   = wave >> 1;
    const int rx   = l31 & 7;            // read-side XOR key (row&7)

    floatx16 acc[2][2];
    const floatx16 z16 = {0.f,0.f,0.f,0.f,0.f,0.f,0.f,0.f,0.f,0.f,0.f,0.f,0.f,0.f,0.f,0.f};
    acc[0][0] = z16; acc[0][1] = z16; acc[1][0] = z16; acc[1][1] = z16;

    for (int kb = 0; kb < IN_F / 2; kb += BK) {    // 16 iterations
#pragma unroll
        for (int i = 0; i < 8; ++i) {
            __builtin_amdgcn_global_load_lds((gvoid*)(aBase + (size_t)i * 16 * IN_F + kb),
                (__attribute__((address_space(3))) void*)(sA3 + i * 2048 + wave * 512),
                16, 0, 0);
            __builtin_amdgcn_global_load_lds((gvoid*)(bBase + (size_t)i * 16 * IN_F + kb),
                (__attribute__((address_space(3))) void*)(sB3 + i * 2048 + wave * 512),
                16, 0, 0);
        }
        __syncthreads();   // tiles visible

#pragma unroll
        for (int ks = 0; ks < 8; ++ks) {     // K-steps of 16
            const int p = ((2 * ks + lhi) ^ rx) * 8;   // swizzled chunk -> ushort offset
            short8 a0 = *(const short8*)&shA[(qm * 64 +      l31) * BK + p];
            short8 a1 = *(const short8*)&shA[(qm * 64 + 32 + l31) * BK + p];
            short8 b0 = *(const short8*)&shB[(qn * 64 +      l31) * BK + p];
            short8 b1 = *(const short8*)&shB[(qn * 64 + 32 + l31) * BK + p];
            acc[0][0] = __builtin_amdgcn_mfma_f32_32x32x16_bf16(a0, b0, acc[0][0], 0, 0, 0);
            acc[0][1] = __builtin_amdgcn_mfma_f32_32x32x16_bf16(a0, b1, acc[0][1], 0, 0, 0);
            acc[1][0] = __builtin_amdgcn_mfma_f32_32x32x16_bf16(a1, b0, acc[1][0], 0, 0, 0);
            acc[1][1] = __builtin_amdgcn_mfma_f32_32x32x16_bf16(a1, b1, acc[1][1], 0, 0, 0);
        }
        __syncthreads();   // all reads done before next staging
    }

    // epilogue: raw partial (scale applied in reduce).
    float* pz = part + (size_t)blockIdx.z * M_TOT * OUT_F;
#pragma unroll
    for (int nt = 0; nt < 2; ++nt) {
        const int col = n0 + qn * 64 + nt * 32 + l31;
#pragma unroll
        for (int mt = 0; mt < 2; ++mt) {
            const int rbase = m0 + qm * 64 + mt * 32 + 4 * lhi;
#pragma unroll
            for (int reg = 0; reg < 16; ++reg) {
                const int row = rbase + (reg & 3) + 8 * (reg >> 2);
                pz[(size_t)row * OUT_F + col] = acc[mt][nt][reg];
            }
        }
    }
}

// Kernel 3: out = (p0 + p1) * scale[col].  4.19M elems, float4, 4096 blocks.
__global__ void reduce_kernel(const float* __restrict__ p0, const float* __restrict__ p1,
                              const float* __restrict__ scale, float* __restrict__ out)
{
    const int i = (blockIdx.x * 256 + threadIdx.x) * 4;
    float4 a = *(const float4*)(p0 + i);
    float4 b = *(const float4*)(p1 + i);
    float4 s = *(const float4*)(scale + (i & (OUT_F - 1)));
    float4 r;
    r.x = (a.x + b.x) * s.x;
    r.y = (a.y + b.y) * s.y;
    r.z = (a.z + b.z) * s.z;
    r.w = (a.w + b.w) * s.w;
    *(float4*)(out + i) = r;
}

// ---------------------------------------------------------------------------
// Fallback A: round-4 single-shot GEMM (scale in epilogue) if ws lacks room
// for partials.
__global__ __launch_bounds__(256)
void gemm_full_kernel(const ushort_t* __restrict__ xb, const ushort_t* __restrict__ wq,
                      const float* __restrict__ scale, float* __restrict__ out)
{
    __shared__ ushort_t shA[128 * BK];
    __shared__ ushort_t shB[128 * BK];

    const int tid  = threadIdx.x;
    const int wave = tid >> 6;
    const int m0   = blockIdx.x * 128;
    const int n0   = blockIdx.y * 128;

    const int g = (tid & 15) ^ ((tid >> 4) & 7);
    const ushort_t* aBase = xb + (size_t)(m0 + (tid >> 4)) * IN_F + g * 8;
    const ushort_t* bBase = wq + (size_t)(n0 + (tid >> 4)) * IN_F + g * 8;
    typedef __attribute__((address_space(3))) ushort_t lds_us;
    typedef const __attribute__((address_space(1))) void gvoid;
    lds_us* sA3 = (lds_us*)shA;
    lds_us* sB3 = (lds_us*)shB;

    const int lane = tid & 63;
    const int l31  = lane & 31;
    const int lhi  = lane >> 5;
    const int qm   = wave & 1;
    const int qn   = wave >> 1;
    const int rx   = l31 & 7;

    floatx16 acc[2][2];
    const floatx16 z16 = {0.f,0.f,0.f,0.f,0.f,0.f,0.f,0.f,0.f,0.f,0.f,0.f,0.f,0.f,0.f,0.f};
    acc[0][0] = z16; acc[0][1] = z16; acc[1][0] = z16; acc[1][1] = z16;

    for (int kb = 0; kb < IN_F; kb += BK) {
#pragma unroll
        for (int i = 0; i < 8; ++i) {
            __builtin_amdgcn_global_load_lds((gvoid*)(aBase + (size_t)i * 16 * IN_F + kb),
                (__attribute__((address_space(3))) void*)(sA3 + i * 2048 + wave * 512), 16, 0, 0);
            __builtin_amdgcn_global_load_lds((gvoid*)(bBase + (size_t)i * 16 * IN_F + kb),
                (__attribute__((address_space(3))) void*)(sB3 + i * 2048 + wave * 512), 16, 0, 0);
        }
        __syncthreads();
#pragma unroll
        for (int ks = 0; ks < 8; ++ks) {
            const int p = ((2 * ks + lhi) ^ rx) * 8;
            short8 a0 = *(const short8*)&shA[(qm * 64 +      l31) * BK + p];
            short8 a1 = *(const short8*)&shA[(qm * 64 + 32 + l31) * BK + p];
            short8 b0 = *(const short8*)&shB[(qn * 64 +      l31) * BK + p];
            short8 b1 = *(const short8*)&shB[(qn * 64 + 32 + l31) * BK + p];
            acc[0][0] = __builtin_amdgcn_mfma_f32_32x32x16_bf16(a0, b0, acc[0][0], 0, 0, 0);
            acc[0][1] = __builtin_amdgcn_mfma_f32_32x32x16_bf16(a0, b1, acc[0][1], 0, 0, 0);
            acc[1][0] = __builtin_amdgcn_mfma_f32_32x32x16_bf16(a1, b0, acc[1][0], 0, 0, 0);
            acc[1][1] = __builtin_amdgcn_mfma_f32_32x32x16_bf16(a1, b1, acc[1][1], 0, 0, 0);
        }
        __syncthreads();
    }
#pragma unroll
    for (int nt = 0; nt < 2; ++nt) {
        const int col = n0 + qn * 64 + nt * 32 + l31;
        const float sc = scale[col];
#pragma unroll
        for (int mt = 0; mt < 2; ++mt) {
            const int rbase = m0 + qm * 64 + mt * 32 + 4 * lhi;
#pragma unroll
            for (int reg = 0; reg < 16; ++reg) {
                const int row = rbase + (reg & 3) + 8 * (reg >> 2);
                out[(size_t)row * OUT_F + col] = acc[mt][nt][reg] * sc;
            }
        }
    }
}

// ---------------------------------------------------------------------------
// Fallback B: round-2 fused kernel (workspace too small for wq).
#define NB  32
#define FBK 128
#define WS  136
#define NITER (IN_F / FBK)
template<bool XBF16>
__global__ __launch_bounds__(1024, 4)
void ghost_kernel(const float* __restrict__ xf, const ushort_t* __restrict__ xb,
                  const int* __restrict__ base_idx, const int* __restrict__ fine_idx,
                  const float* __restrict__ scale, const float* __restrict__ lut,
                  float* __restrict__ out)
{
    __shared__ ushort_t sh_lut[65536];
    __shared__ ushort_t sh_w[2][NB * WS];
    const int tid = threadIdx.x;
    const int n0  = blockIdx.x * NB;
    for (int i = tid * 4; i < 65536; i += 1024 * 4) {
        float4 v = *(const float4*)(lut + i);
        sh_lut[i + 0] = f2bf(v.x); sh_lut[i + 1] = f2bf(v.y);
        sh_lut[i + 2] = f2bf(v.z); sh_lut[i + 3] = f2bf(v.w);
    }
    const int sn  = tid >> 5;
    const int skq = (tid & 31) * 4;
    const int* bp = base_idx + (size_t)(n0 + sn) * IN_F + skq;
    const int* fp = fine_idx + (size_t)(n0 + sn) * IN_F + skq;
    __syncthreads();
    int4 pb = *(const int4*)(bp);
    int4 pf = *(const int4*)(fp);
    {
        uint32 w0 = (uint32)sh_lut[(pb.x << 8) + pf.x] | ((uint32)sh_lut[(pb.y << 8) + pf.y] << 16);
        uint32 w1 = (uint32)sh_lut[(pb.z << 8) + pf.z] | ((uint32)sh_lut[(pb.w << 8) + pf.w] << 16);
        uint2 wv; wv.x = w0; wv.y = w1;
        *(uint2*)&sh_w[0][sn * WS + skq] = wv;
    }
    pb = *(const int4*)(bp + FBK);
    pf = *(const int4*)(fp + FBK);
    __syncthreads();
    const int lane = tid & 63;
    const int wave = tid >> 6;
    const int l16  = lane & 15;
    const int quad = lane >> 4;
    floatx4 acc[2][2];
    const floatx4 zero = {0.f, 0.f, 0.f, 0.f};
    acc[0][0] = zero; acc[0][1] = zero; acc[1][0] = zero; acc[1][1] = zero;
    const int mrow = wave * 32 + l16;
    const ushort_t* xrow  = XBF16 ? (xb + (size_t)mrow * IN_F + quad * 8) : (const ushort_t*)nullptr;
    const float*    xrowf = XBF16 ? (const float*)nullptr : (xf + (size_t)mrow * IN_F + quad * 8);
    for (int t = 0; t < NITER; ++t) {
        const int k0 = t * FBK;
        {
            uint32 w0 = (uint32)sh_lut[(pb.x << 8) + pf.x] | ((uint32)sh_lut[(pb.y << 8) + pf.y] << 16);
            uint32 w1 = (uint32)sh_lut[(pb.z << 8) + pf.z] | ((uint32)sh_lut[(pb.w << 8) + pf.w] << 16);
            uint2 wv; wv.x = w0; wv.y = w1;
            *(uint2*)&sh_w[(t + 1) & 1][sn * WS + skq] = wv;
        }
        {
            const int kk = (t + 2 < NITER ? t + 2 : NITER - 1) * FBK;
            pb = *(const int4*)(bp + kk);
            pf = *(const int4*)(fp + kk);
        }
        const ushort_t* wb = sh_w[t & 1];
#pragma unroll
        for (int ks = 0; ks < 4; ++ks) {
            const int kk = k0 + ks * 32;
            short8 b0 = *(const short8*)&wb[l16        * WS + ks * 32 + quad * 8];
            short8 b1 = *(const short8*)&wb[(16 + l16) * WS + ks * 32 + quad * 8];
            short8 a0, a1;
            if (XBF16) {
                a0 = *(const short8*)(xrow + kk);
                a1 = *(const short8*)(xrow + (size_t)16 * IN_F + kk);
            } else {
                const float* p0 = xrowf + kk;
                const float* p1 = xrowf + (size_t)16 * IN_F + kk;
                float4 u0 = *(const float4*)p0, u1 = *(const float4*)(p0 + 4);
                float4 v0 = *(const float4*)p1, v1 = *(const float4*)(p1 + 4);
                a0[0] = (short)f2bf(u0.x); a0[1] = (short)f2bf(u0.y);
                a0[2] = (short)f2bf(u0.z); a0[3] = (short)f2bf(u0.w);
                a0[4] = (short)f2bf(u1.x); a0[5] = (short)f2bf(u1.y);
                a0[6] = (short)f2bf(u1.z); a0[7] = (short)f2bf(u1.w);
                a1[0] = (short)f2bf(v0.x); a1[1] = (short)f2bf(v0.y);
                a1[2] = (short)f2bf(v0.z); a1[3] = (short)f2bf(v0.w);
                a1[4] = (short)f2bf(v1.x); a1[5] = (short)f2bf(v1.y);
                a1[6] = (short)f2bf(v1.z); a1[7] = (short)f2bf(v1.w);
            }
            acc[0][0] = __builtin_amdgcn_mfma_f32_16x16x32_bf16(a0, b0, acc[0][0], 0, 0, 0);
            acc[0][1] = __builtin_amdgcn_mfma_f32_16x16x32_bf16(a0, b1, acc[0][1], 0, 0, 0);
            acc[1][0] = __builtin_amdgcn_mfma_f32_16x16x32_bf16(a1, b0, acc[1][0], 0, 0, 0);
            acc[1][1] = __builtin_amdgcn_mfma_f32_16x16x32_bf16(a1, b1, acc[1][1], 0, 0, 0);
        }
        __syncthreads();
    }
#pragma unroll
    for (int nf = 0; nf < 2; ++nf) {
        const int col = n0 + nf * 16 + l16;
        const float sc = scale[col];
#pragma unroll
        for (int f = 0; f < 2; ++f) {
            const int r0 = wave * 32 + f * 16 + quad * 4;
#pragma unroll
            for (int r = 0; r < 4; ++r) {
                out[(size_t)(r0 + r) * OUT_F + col] = acc[f][nf][r] * sc;
            }
        }
    }
}

// ---------------------------------------------------------------------------
extern "C" void kernel_launch(void* const* d_in, const int* in_sizes, int n_in,
                              void* d_out, int out_size, void* d_ws, size_t ws_size,
                              hipStream_t stream) {
    const float* x      = (const float*)d_in[0];
    const int*   bidx   = (const int*)d_in[1];
    const int*   fidx   = (const int*)d_in[2];
    const float* scale  = (const float*)d_in[3];
    const float* lut    = (const float*)d_in[4];
    float*       out    = (float*)d_out;

    const size_t xb_bytes = (size_t)M_TOT * IN_F * sizeof(ushort_t);   // 4 MB
    const size_t wq_bytes = (size_t)OUT_F * IN_F * sizeof(ushort_t);   // 64 MB
    const size_t pt_bytes = (size_t)M_TOT * OUT_F * sizeof(float);     // 16.8 MB each

    if (ws_size >= xb_bytes + wq_bytes + 2 * pt_bytes) {
        ushort_t* xbuf = (ushort_t*)d_ws;
        ushort_t* wbuf = (ushort_t*)((char*)d_ws + xb_bytes);
        float*    part = (float*)((char*)d_ws + xb_bytes + wq_bytes);
        cvt_x_kernel<<<1024, 256, 0, stream>>>(x, xbuf);
        dequant_kernel<<<256, 1024, 0, stream>>>(bidx, fidx, lut, wbuf);
        gemm_split_kernel<<<dim3(4, 64, 2), 256, 0, stream>>>(xbuf, wbuf, part);
        reduce_kernel<<<(M_TOT * OUT_F) / (256 * 4), 256, 0, stream>>>(
            part, part + (size_t)M_TOT * OUT_F, scale, out);
    } else if (ws_size >= xb_bytes + wq_bytes) {
        ushort_t* xbuf = (ushort_t*)d_ws;
        ushort_t* wbuf = (ushort_t*)((char*)d_ws + xb_bytes);
        cvt_x_kernel<<<1024, 256, 0, stream>>>(x, xbuf);
        dequant_kernel<<<256, 1024, 0, stream>>>(bidx, fidx, lut, wbuf);
        gemm_full_kernel<<<dim3(4, 64), 256, 0, stream>>>(xbuf, wbuf, scale, out);
    } else if (ws_size >= xb_bytes) {
        ushort_t* xbuf = (ushort_t*)d_ws;
        cvt_x_kernel<<<1024, 256, 0, stream>>>(x, xbuf);
        ghost_kernel<true><<<OUT_F / NB, 1024, 0, stream>>>(x, xbuf, bidx, fidx, scale, lut, out);
    } else {
        ghost_kernel<false><<<OUT_F / NB, 1024, 0, stream>>>(x, nullptr, bidx, fidx, scale, lut, out);
    }
}

// Round 2
// 344.581 us; speedup vs baseline: 1.0575x; 1.0573x over previous
//
#include <hip/hip_runtime.h>

typedef unsigned short ushort_t;
typedef unsigned int   uint32;
typedef __attribute__((ext_vector_type(8)))  short short8;    // 8 x bf16 (4 VGPRs)
typedef __attribute__((ext_vector_type(4)))  float floatx4;
typedef __attribute__((ext_vector_type(16))) float floatx16;  // 32x32 MFMA accumulator

#define IN_F   4096
#define OUT_F  8192
#define M_TOT  512

__device__ __forceinline__ ushort_t f2bf(float f) {
    uint32 u = __builtin_bit_cast(uint32, f);
    u += 0x7FFFu + ((u >> 16) & 1u);    // RNE
    return (ushort_t)(u >> 16);
}
__device__ __forceinline__ uint32 pack2bf(float a, float b) {
    return (uint32)f2bf(a) | ((uint32)f2bf(b) << 16);
}

// ---------------------------------------------------------------------------
// Kernel 0: x fp32 -> bf16, MFMA-blocked layout XB[mt][kt][32][16]:
// ushort offset = ((mt*256 + kt)*32 + (m&31))*16 + (k&15),  mt=m>>5, kt=k>>4.
// This makes each 32x32x16 A-fragment (32 rows x 16 k) one contiguous 1 KB
// segment -> fully-coalesced per-lane 16B loads in the fused GEMM (the flat
// row-major layout would be 32 scattered 32B segments per A-load).
__global__ void cvt_x_kernel(const float* __restrict__ x, ushort_t* __restrict__ xb) {
    const int g  = blockIdx.x * 256 + threadIdx.x;   // 262144 threads total
    const int r  = g >> 9;                           // row 0..511
    const int k0 = (g & 511) * 8;                    // k octet
    float4 v0 = *(const float4*)(x + (size_t)r * IN_F + k0);
    float4 v1 = *(const float4*)(x + (size_t)r * IN_F + k0 + 4);
    short8 s;
    s[0] = (short)f2bf(v0.x); s[1] = (short)f2bf(v0.y);
    s[2] = (short)f2bf(v0.z); s[3] = (short)f2bf(v0.w);
    s[4] = (short)f2bf(v1.x); s[5] = (short)f2bf(v1.y);
    s[6] = (short)f2bf(v1.z); s[7] = (short)f2bf(v1.w);
    const int mt = r >> 5;
    const int kt = k0 >> 4;
    ushort_t* dst = xb + ((size_t)(mt * 256 + kt) * 32 + (r & 31)) * 16 + (k0 & 15);
    *(short8*)dst = s;
}

// ---------------------------------------------------------------------------
// Fused dequant + GEMM + scale.  Round-1 rewrite rationale: top-5 counters
// show dequant 105us (all slots), gemm <=102, and ~140us of wall time outside
// any dispatch (inter-kernel gaps) + 212 MB of intermediate traffic (wq,
// partials).  Fusing reads the 268 MB index stream ONCE (the true 42us HBM
// floor), keeps W entirely in LDS tile-by-tile, and writes only `out`.
//
// Partition: 256 blocks (1/CU), block b owns w-rows / out-cols [32b,32b+32)
// for ALL m,k -> indices touched exactly once.  1024 thr = 16 waves; wave w
// computes the 32x32 out-tile rows [32w,32w+32).  LDS: bf16 LUT 128 KB +
// double-buffered 32x64 w-tile 8 KB = 136 KB (1 block/CU, 4 waves/SIMD).
// Per K-iter (BK=64): each thread dequants 2 elems of tile t+1 (indices
// register-prefetched 2 tiles ahead), B-frags read from XOR-swizzled sh_w,
// A-frags loaded straight from the blocked xb (L2-resident, coalesced 1KB),
// 4 MFMA per wave, one __syncthreads.
__global__ __launch_bounds__(1024, 4)
void fused_kernel(const ushort_t* __restrict__ xb, const int* __restrict__ base_idx,
                  const int* __restrict__ fine_idx, const float* __restrict__ lut,
                  const float* __restrict__ scale, float* __restrict__ out)
{
    __shared__ ushort_t sh_lut[65536];        // 128 KB bf16 LUT
    __shared__ ushort_t sh_w[2][32 * 64];     // 2 x 4 KB w-tiles

    const int tid  = threadIdx.x;
    const int nblk = blockIdx.x;              // col-block: cols [32*nblk, +32)

    // Stage LUT fp32 -> bf16 (each thread 64 entries).
    for (int i = tid * 4; i < 65536; i += 4096) {
        float4 v = *(const float4*)(lut + i);
        *(uint32*)&sh_lut[i]     = pack2bf(v.x, v.y);
        *(uint32*)&sh_lut[i + 2] = pack2bf(v.z, v.w);
    }

    // Dequant role: thread -> (col = tid>>5, k-pair kp within 64-wide tile).
    const int colr = tid >> 5;                // 0..31
    const int kp   = (tid & 31) * 2;          // 0,2,..,62
    const int2* bp = (const int2*)(base_idx + (size_t)(nblk * 32 + colr) * IN_F + kp);
    const int2* fp = (const int2*)(fine_idx + (size_t)(nblk * 32 + colr) * IN_F + kp);
    // tile t lives at bp[t*32] (64 ints = 32 int2 per tile)
    int2 cb = bp[0],  cf = fp[0];             // indices for tile 0 (then t+1)
    int2 nb = bp[32], nf = fp[32];            // indices for tile 1 (then t+2)

    // Swizzled sh_w offset for this thread's packed write.  Element (col,k):
    // ushort addr = col*64 + ((k>>3) ^ (col&7))*8 + (k&7).  kp is even and
    // kp,kp+1 share a chunk -> one aligned b32 write.
    const int woff = colr * 64 + ((((kp >> 3) ^ (colr & 7))) << 3) + (kp & 7);

    const int lane = tid & 63;
    const int wave = tid >> 6;                // 0..15 = m-tile index
    const int l31  = lane & 31;
    const int lhi  = lane >> 5;

    __syncthreads();                          // LUT ready

    {   // dequant tile 0 into sh_w[0]
        uint32 w = (uint32)sh_lut[(cb.x << 8) + cf.x]
                 | ((uint32)sh_lut[(cb.y << 8) + cf.y] << 16);
        *(uint32*)&sh_w[0][woff] = w;
    }
    cb = nb; cf = nf;                         // cb/cf = tile 1
    nb = bp[64]; nf = fp[64];                 // nb/nf = tile 2
    __syncthreads();                          // tile 0 visible

    floatx16 acc = {0.f,0.f,0.f,0.f,0.f,0.f,0.f,0.f,0.f,0.f,0.f,0.f,0.f,0.f,0.f,0.f};

    // Blocked A base: XB tile (mt=wave, kt) is 512 ushorts; lane's slot inside
    // a tile is l31*16 + lhi*8 (8 contiguous bf16 = 16 B).
    const ushort_t* abase = xb + (size_t)wave * 256 * 512 + l31 * 16 + lhi * 8;
    const int rx8 = (l31 & 7);                // read-side swizzle key

#pragma unroll 2
    for (int t = 0; t < 64; ++t) {            // 64 K-iters of BK=64
        const int cur = t & 1;

        // A-fragments: 4 coalesced 16B loads from L2-resident blocked xb.
        short8 a0 = *(const short8*)(abase + (size_t)(t * 4 + 0) * 512);
        short8 a1 = *(const short8*)(abase + (size_t)(t * 4 + 1) * 512);
        short8 a2 = *(const short8*)(abase + (size_t)(t * 4 + 2) * 512);
        short8 a3 = *(const short8*)(abase + (size_t)(t * 4 + 3) * 512);

        // B-fragments from current w-tile (chunk = ks*2 + lhi, XOR-swizzled).
        const ushort_t* wb = sh_w[cur];
        short8 b0 = *(const short8*)&wb[l31 * 64 + (((0 + lhi) ^ rx8) << 3)];
        short8 b1 = *(const short8*)&wb[l31 * 64 + (((2 + lhi) ^ rx8) << 3)];
        short8 b2 = *(const short8*)&wb[l31 * 64 + (((4 + lhi) ^ rx8) << 3)];
        short8 b3 = *(const short8*)&wb[l31 * 64 + (((6 + lhi) ^ rx8) << 3)];

        // Dequant next tile into the other buffer (indices already in regs).
        if (t + 1 < 64) {
            uint32 w = (uint32)sh_lut[(cb.x << 8) + cf.x]
                     | ((uint32)sh_lut[(cb.y << 8) + cf.y] << 16);
            *(uint32*)&sh_w[cur ^ 1][woff] = w;
            cb = nb; cf = nf;
            if (t + 3 < 64) { nb = bp[(t + 3) * 32]; nf = fp[(t + 3) * 32]; }
        }

        acc = __builtin_amdgcn_mfma_f32_32x32x16_bf16(a0, b0, acc, 0, 0, 0);
        acc = __builtin_amdgcn_mfma_f32_32x32x16_bf16(a1, b1, acc, 0, 0, 0);
        acc = __builtin_amdgcn_mfma_f32_32x32x16_bf16(a2, b2, acc, 0, 0, 0);
        acc = __builtin_amdgcn_mfma_f32_32x32x16_bf16(a3, b3, acc, 0, 0, 0);

        __syncthreads();   // next tile written + this tile's reads done
    }

    // Epilogue: out[row][col] = acc * scale[col]   (C/D: col=l31, row mapping
    // verified in the previous gemm_split kernel).
    const float sc = scale[nblk * 32 + l31];
    float* op = out + (size_t)(nblk * 32 + l31);
    const int rbase = wave * 32 + 4 * lhi;
#pragma unroll
    for (int reg = 0; reg < 16; ++reg) {
        const int row = rbase + (reg & 3) + 8 * (reg >> 2);
        op[(size_t)row * OUT_F] = acc[reg] * sc;
    }
}

// ---------------------------------------------------------------------------
// Fallback: round-2 fused kernel for tiny workspace (x read as fp32).
#define NB  32
#define FBK 128
#define WS  136
#define NITER (IN_F / FBK)
__global__ __launch_bounds__(1024, 4)
void ghost_kernel(const float* __restrict__ xf,
                  const int* __restrict__ base_idx, const int* __restrict__ fine_idx,
                  const float* __restrict__ scale, const float* __restrict__ lut,
                  float* __restrict__ out)
{
    __shared__ ushort_t sh_lut[65536];
    __shared__ ushort_t sh_w[2][NB * WS];
    const int tid = threadIdx.x;
    const int n0  = blockIdx.x * NB;
    for (int i = tid * 4; i < 65536; i += 1024 * 4) {
        float4 v = *(const float4*)(lut + i);
        sh_lut[i + 0] = f2bf(v.x); sh_lut[i + 1] = f2bf(v.y);
        sh_lut[i + 2] = f2bf(v.z); sh_lut[i + 3] = f2bf(v.w);
    }
    const int sn  = tid >> 5;
    const int skq = (tid & 31) * 4;
    const int* bp = base_idx + (size_t)(n0 + sn) * IN_F + skq;
    const int* fp = fine_idx + (size_t)(n0 + sn) * IN_F + skq;
    __syncthreads();
    int4 pb = *(const int4*)(bp);
    int4 pf = *(const int4*)(fp);
    {
        uint32 w0 = (uint32)sh_lut[(pb.x << 8) + pf.x] | ((uint32)sh_lut[(pb.y << 8) + pf.y] << 16);
        uint32 w1 = (uint32)sh_lut[(pb.z << 8) + pf.z] | ((uint32)sh_lut[(pb.w << 8) + pf.w] << 16);
        uint2 wv; wv.x = w0; wv.y = w1;
        *(uint2*)&sh_w[0][sn * WS + skq] = wv;
    }
    pb = *(const int4*)(bp + FBK);
    pf = *(const int4*)(fp + FBK);
    __syncthreads();
    const int lane = tid & 63;
    const int wave = tid >> 6;
    const int l16  = lane & 15;
    const int quad = lane >> 4;
    floatx4 acc[2][2];
    const floatx4 zero = {0.f, 0.f, 0.f, 0.f};
    acc[0][0] = zero; acc[0][1] = zero; acc[1][0] = zero; acc[1][1] = zero;
    const int mrow = wave * 32 + l16;
    const float* xrowf = xf + (size_t)mrow * IN_F + quad * 8;
    for (int t = 0; t < NITER; ++t) {
        const int k0 = t * FBK;
        {
            uint32 w0 = (uint32)sh_lut[(pb.x << 8) + pf.x] | ((uint32)sh_lut[(pb.y << 8) + pf.y] << 16);
            uint32 w1 = (uint32)sh_lut[(pb.z << 8) + pf.z] | ((uint32)sh_lut[(pb.w << 8) + pf.w] << 16);
            uint2 wv; wv.x = w0; wv.y = w1;
            *(uint2*)&sh_w[(t + 1) & 1][sn * WS + skq] = wv;
        }
        {
            const int kk = (t + 2 < NITER ? t + 2 : NITER - 1) * FBK;
            pb = *(const int4*)(bp + kk);
            pf = *(const int4*)(fp + kk);
        }
        const ushort_t* wb = sh_w[t & 1];
#pragma unroll
        for (int ks = 0; ks < 4; ++ks) {
            const int kk = k0 + ks * 32;
            short8 b0 = *(const short8*)&wb[l16        * WS + ks * 32 + quad * 8];
            short8 b1 = *(const short8*)&wb[(16 + l16) * WS + ks * 32 + quad * 8];
            short8 a0, a1;
            const float* p0 = xrowf + kk;
            const float* p1 = xrowf + (size_t)16 * IN_F + kk;
            float4 u0 = *(const float4*)p0, u1 = *(const float4*)(p0 + 4);
            float4 v0 = *(const float4*)p1, v1 = *(const float4*)(p1 + 4);
            a0[0] = (short)f2bf(u0.x); a0[1] = (short)f2bf(u0.y);
            a0[2] = (short)f2bf(u0.z); a0[3] = (short)f2bf(u0.w);
            a0[4] = (short)f2bf(u1.x); a0[5] = (short)f2bf(u1.y);
            a0[6] = (short)f2bf(u1.z); a0[7] = (short)f2bf(u1.w);
            a1[0] = (short)f2bf(v0.x); a1[1] = (short)f2bf(v0.y);
            a1[2] = (short)f2bf(v0.z); a1[3] = (short)f2bf(v0.w);
            a1[4] = (short)f2bf(v1.x); a1[5] = (short)f2bf(v1.y);
            a1[6] = (short)f2bf(v1.z); a1[7] = (short)f2bf(v1.w);
            acc[0][0] = __builtin_amdgcn_mfma_f32_16x16x32_bf16(a0, b0, acc[0][0], 0, 0, 0);
            acc[0][1] = __builtin_amdgcn_mfma_f32_16x16x32_bf16(a0, b1, acc[0][1], 0, 0, 0);
            acc[1][0] = __builtin_amdgcn_mfma_f32_16x16x32_bf16(a1, b0, acc[1][0], 0, 0, 0);
            acc[1][1] = __builtin_amdgcn_mfma_f32_16x16x32_bf16(a1, b1, acc[1][1], 0, 0, 0);
        }
        __syncthreads();
    }
#pragma unroll
    for (int nf = 0; nf < 2; ++nf) {
        const int col = n0 + nf * 16 + l16;
        const float sc = scale[col];
#pragma unroll
        for (int f = 0; f < 2; ++f) {
            const int r0 = wave * 32 + f * 16 + quad * 4;
#pragma unroll
            for (int r = 0; r < 4; ++r) {
                out[(size_t)(r0 + r) * OUT_F + col] = acc[f][nf][r] * sc;
            }
        }
    }
}

// ---------------------------------------------------------------------------
extern "C" void kernel_launch(void* const* d_in, const int* in_sizes, int n_in,
                              void* d_out, int out_size, void* d_ws, size_t ws_size,
                              hipStream_t stream) {
    const float* x      = (const float*)d_in[0];
    const int*   bidx   = (const int*)d_in[1];
    const int*   fidx   = (const int*)d_in[2];
    const float* scale  = (const float*)d_in[3];
    const float* lut    = (const float*)d_in[4];
    float*       out    = (float*)d_out;

    const size_t xb_bytes = (size_t)M_TOT * IN_F * sizeof(ushort_t);   // 4 MB

    if (ws_size >= xb_bytes) {
        ushort_t* xbuf = (ushort_t*)d_ws;
        cvt_x_kernel<<<1024, 256, 0, stream>>>(x, xbuf);
        fused_kernel<<<256, 1024, 0, stream>>>(xbuf, bidx, fidx, lut, scale, out);
    } else {
        ghost_kernel<<<OUT_F / NB, 1024, 0, stream>>>(x, bidx, fidx, scale, lut, out);
    }
}

// Round 5
// 325.979 us; speedup vs baseline: 1.1179x; 1.0571x over previous
//
#include <hip/hip_runtime.h>

typedef unsigned short ushort_t;
typedef unsigned int   uint32;
typedef __attribute__((ext_vector_type(8)))  short short8;    // 8 x bf16 (4 VGPRs)
typedef __attribute__((ext_vector_type(4)))  float floatx4;
typedef __attribute__((ext_vector_type(16))) float floatx16;  // 32x32 MFMA accumulator

#define IN_F   4096
#define OUT_F  8192
#define M_TOT  512

__device__ __forceinline__ ushort_t f2bf(float f) {
    uint32 u = __builtin_bit_cast(uint32, f);
    u += 0x7FFFu + ((u >> 16) & 1u);    // RNE
    return (ushort_t)(u >> 16);
}
__device__ __forceinline__ uint32 pack2bf(float a, float b) {
    return (uint32)f2bf(a) | ((uint32)f2bf(b) << 16);
}

// ---------------------------------------------------------------------------
// Kernel 0: x fp32 -> bf16, MFMA-blocked layout XB[mt][kt][32][16]:
// ushort offset = ((mt*256 + kt)*32 + (m&31))*16 + (k&15),  mt=m>>5, kt=k>>4.
// Each 32x32x16 A-fragment is one contiguous 1 KB segment -> per-lane 16B
// fully-coalesced loads in the fused GEMM.
__global__ void cvt_x_kernel(const float* __restrict__ x, ushort_t* __restrict__ xb) {
    const int g  = blockIdx.x * 256 + threadIdx.x;   // 262144 threads total
    const int r  = g >> 9;                           // row 0..511
    const int k0 = (g & 511) * 8;                    // k octet
    float4 v0 = *(const float4*)(x + (size_t)r * IN_F + k0);
    float4 v1 = *(const float4*)(x + (size_t)r * IN_F + k0 + 4);
    short8 s;
    s[0] = (short)f2bf(v0.x); s[1] = (short)f2bf(v0.y);
    s[2] = (short)f2bf(v0.z); s[3] = (short)f2bf(v0.w);
    s[4] = (short)f2bf(v1.x); s[5] = (short)f2bf(v1.y);
    s[6] = (short)f2bf(v1.z); s[7] = (short)f2bf(v1.w);
    const int mt = r >> 5;
    const int kt = k0 >> 4;
    ushort_t* dst = xb + ((size_t)(mt * 256 + kt) * 32 + (r & 31)) * 16 + (k0 & 15);
    *(short8*)dst = s;
}

// ---------------------------------------------------------------------------
// Fused dequant + GEMM + scale, round-2/3 schedule rewrite (round-4 resubmit
// after infra failure — unchanged, measurement still pending).
//
// Round-1 counters: 150us, MfmaUtil 8.7%, 1.13 TB/s vs ~55us overlapped floor
// (268MB idx HBM + 1.07GB A from L2).  Diagnosis: __syncthreads() every 64-k
// iter (64 barriers) forces s_waitcnt vmcnt(0) -> the whole VMEM queue (HBM
// index prefetch ~900cy + A-loads) drains at EVERY barrier, 1 block/CU = no
// other block to hide it.  Register prefetch was nullified by the drain.
//
// Fix (T3/T4): raw s_barrier with lgkmcnt(0)-ONLY drain (LDS double-buffer
// needs ds-ops drained, NOT vmem); vmcnt never hits 0 in the main loop, so
// index/A loads stay in flight across barriers.  BK 64->128: 32 iters, 8
// MFMA/wave/iter, barrier count halved.  LDS: LUT 128KB + 2x8KB w-tiles.
__global__ __launch_bounds__(1024, 4)
void fused_kernel(const ushort_t* __restrict__ xb, const int* __restrict__ base_idx,
                  const int* __restrict__ fine_idx, const float* __restrict__ lut,
                  const float* __restrict__ scale, float* __restrict__ out)
{
    __shared__ ushort_t sh_lut[65536];        // 128 KB bf16 LUT
    __shared__ ushort_t sh_w[2][32 * 128];    // 2 x 8 KB w-tiles (BK=128)

    const int tid  = threadIdx.x;
    const int nblk = blockIdx.x;              // col-block: cols [32*nblk, +32)

    // Stage LUT fp32 -> bf16 (each thread 64 entries).
    for (int i = tid * 4; i < 65536; i += 4096) {
        float4 v = *(const float4*)(lut + i);
        *(uint32*)&sh_lut[i]     = pack2bf(v.x, v.y);
        *(uint32*)&sh_lut[i + 2] = pack2bf(v.z, v.w);
    }

    // Dequant role: thread -> (col = tid>>5, k-quad kq within 128-wide tile).
    const int colr = tid >> 5;                // 0..31
    const int kq   = (tid & 31) * 4;          // 0,4,..,124
    const int4* bp = (const int4*)(base_idx + (size_t)(nblk * 32 + colr) * IN_F + kq);
    const int4* fp = (const int4*)(fine_idx + (size_t)(nblk * 32 + colr) * IN_F + kq);
    // tile t lives at bp[t*32] (128 ints = 32 int4 per col per tile)

    // Swizzled write offset: elems (colr, kq..kq+3), chunk = kq>>3 (4 bits),
    // slot = chunk ^ (colr&7) on low 3 bits; kq&7 in {0,4} -> one aligned b64.
    const int woff = colr * 128 + (((kq >> 3) ^ (colr & 7)) << 3) + (kq & 7);

    const int lane = tid & 63;
    const int wave = tid >> 6;                // 0..15 = m-tile index
    const int l31  = lane & 31;
    const int lhi  = lane >> 5;
    const int rx8  = l31 & 7;                 // read-side swizzle key

    // Prologue index loads.
    int4 ib0 = bp[0];                         // tile 0
    int4 if0 = fp[0];
    int4 Ib  = bp[32];                        // tile 1
    int4 If  = fp[32];

    __syncthreads();                          // LUT ready (full sync, once)

    {   // dequant tile 0 into sh_w[0]
        uint32 w0 = (uint32)sh_lut[(ib0.x << 8) + if0.x]
                  | ((uint32)sh_lut[(ib0.y << 8) + if0.y] << 16);
        uint32 w1 = (uint32)sh_lut[(ib0.z << 8) + if0.z]
                  | ((uint32)sh_lut[(ib0.w << 8) + if0.w] << 16);
        uint2 wv; wv.x = w0; wv.y = w1;
        *(uint2*)&sh_w[0][woff] = wv;
    }
    int4 Nb = bp[64];                         // tile 2
    int4 Nf = fp[64];

    __syncthreads();                          // tile 0 visible (full sync, once)

    floatx16 acc = {0.f,0.f,0.f,0.f,0.f,0.f,0.f,0.f,0.f,0.f,0.f,0.f,0.f,0.f,0.f,0.f};

    // Blocked A base: XB tile (mt=wave, kt) = 512 ushorts; lane slot l31*16+lhi*8.
    const ushort_t* abase = xb + (size_t)wave * 256 * 512 + l31 * 16 + lhi * 8;

#pragma unroll 2
    for (int t = 0; t < 32; ++t) {            // 32 K-iters of BK=128
        const int cur = t & 1;

        // A-fragments: 8 coalesced 16B loads from L2-resident blocked xb.
        short8 a0 = *(const short8*)(abase + (size_t)(t * 8 + 0) * 512);
        short8 a1 = *(const short8*)(abase + (size_t)(t * 8 + 1) * 512);
        short8 a2 = *(const short8*)(abase + (size_t)(t * 8 + 2) * 512);
        short8 a3 = *(const short8*)(abase + (size_t)(t * 8 + 3) * 512);
        short8 a4 = *(const short8*)(abase + (size_t)(t * 8 + 4) * 512);
        short8 a5 = *(const short8*)(abase + (size_t)(t * 8 + 5) * 512);
        short8 a6 = *(const short8*)(abase + (size_t)(t * 8 + 6) * 512);
        short8 a7 = *(const short8*)(abase + (size_t)(t * 8 + 7) * 512);

        // B-fragments from current w-tile (chunk = ks*2+lhi, XOR-swizzled).
        const ushort_t* wb = sh_w[cur];
        short8 b0 = *(const short8*)&wb[l31 * 128 + ((( 0 + lhi) ^ rx8) << 3)];
        short8 b1 = *(const short8*)&wb[l31 * 128 + ((( 2 + lhi) ^ rx8) << 3)];
        short8 b2 = *(const short8*)&wb[l31 * 128 + ((( 4 + lhi) ^ rx8) << 3)];
        short8 b3 = *(const short8*)&wb[l31 * 128 + ((( 6 + lhi) ^ rx8) << 3)];
        short8 b4 = *(const short8*)&wb[l31 * 128 + ((( 8 + lhi) ^ rx8) << 3)];
        short8 b5 = *(const short8*)&wb[l31 * 128 + (((10 + lhi) ^ rx8) << 3)];
        short8 b6 = *(const short8*)&wb[l31 * 128 + (((12 + lhi) ^ rx8) << 3)];
        short8 b7 = *(const short8*)&wb[l31 * 128 + (((14 + lhi) ^ rx8) << 3)];

        // Dequant tile t+1 into the other buffer; rotate index pipeline.
        if (t < 31) {
            uint32 w0 = (uint32)sh_lut[(Ib.x << 8) + If.x]
                      | ((uint32)sh_lut[(Ib.y << 8) + If.y] << 16);
            uint32 w1 = (uint32)sh_lut[(Ib.z << 8) + If.z]
                      | ((uint32)sh_lut[(Ib.w << 8) + If.w] << 16);
            uint2 wv; wv.x = w0; wv.y = w1;
            *(uint2*)&sh_w[cur ^ 1][woff] = wv;
            Ib = Nb; If = Nf;
            if (t + 3 < 32) {
                Nb = bp[(t + 3) * 32];
                Nf = fp[(t + 3) * 32];
            }
        }

        acc = __builtin_amdgcn_mfma_f32_32x32x16_bf16(a0, b0, acc, 0, 0, 0);
        acc = __builtin_amdgcn_mfma_f32_32x32x16_bf16(a1, b1, acc, 0, 0, 0);
        acc = __builtin_amdgcn_mfma_f32_32x32x16_bf16(a2, b2, acc, 0, 0, 0);
        acc = __builtin_amdgcn_mfma_f32_32x32x16_bf16(a3, b3, acc, 0, 0, 0);
        acc = __builtin_amdgcn_mfma_f32_32x32x16_bf16(a4, b4, acc, 0, 0, 0);
        acc = __builtin_amdgcn_mfma_f32_32x32x16_bf16(a5, b5, acc, 0, 0, 0);
        acc = __builtin_amdgcn_mfma_f32_32x32x16_bf16(a6, b6, acc, 0, 0, 0);
        acc = __builtin_amdgcn_mfma_f32_32x32x16_bf16(a7, b7, acc, 0, 0, 0);

        // Raw barrier with LDS-only drain: ds_reads of tile t + ds_write of
        // tile t+1 must retire block-wide; vmem (idx/A loads) stays in flight.
        asm volatile("s_waitcnt lgkmcnt(0)" ::: "memory");
        __builtin_amdgcn_sched_barrier(0);
        __builtin_amdgcn_s_barrier();
    }

    // Epilogue: out[row][col] = acc * scale[col]  (32x32 C/D mapping:
    // col=l31, row=(reg&3)+8*(reg>>2)+4*lhi — verified in earlier rounds).
    const float sc = scale[nblk * 32 + l31];
    float* op = out + (size_t)(nblk * 32 + l31);
    const int rbase = wave * 32 + 4 * lhi;
#pragma unroll
    for (int reg = 0; reg < 16; ++reg) {
        const int row = rbase + (reg & 3) + 8 * (reg >> 2);
        op[(size_t)row * OUT_F] = acc[reg] * sc;
    }
}

// ---------------------------------------------------------------------------
// Fallback: fused kernel for tiny workspace (x read as fp32).
#define NB  32
#define FBK 128
#define WS  136
#define NITER (IN_F / FBK)
__global__ __launch_bounds__(1024, 4)
void ghost_kernel(const float* __restrict__ xf,
                  const int* __restrict__ base_idx, const int* __restrict__ fine_idx,
                  const float* __restrict__ scale, const float* __restrict__ lut,
                  float* __restrict__ out)
{
    __shared__ ushort_t sh_lut[65536];
    __shared__ ushort_t sh_w[2][NB * WS];
    const int tid = threadIdx.x;
    const int n0  = blockIdx.x * NB;
    for (int i = tid * 4; i < 65536; i += 1024 * 4) {
        float4 v = *(const float4*)(lut + i);
        sh_lut[i + 0] = f2bf(v.x); sh_lut[i + 1] = f2bf(v.y);
        sh_lut[i + 2] = f2bf(v.z); sh_lut[i + 3] = f2bf(v.w);
    }
    const int sn  = tid >> 5;
    const int skq = (tid & 31) * 4;
    const int* bp = base_idx + (size_t)(n0 + sn) * IN_F + skq;
    const int* fp = fine_idx + (size_t)(n0 + sn) * IN_F + skq;
    __syncthreads();
    int4 pb = *(const int4*)(bp);
    int4 pf = *(const int4*)(fp);
    {
        uint32 w0 = (uint32)sh_lut[(pb.x << 8) + pf.x] | ((uint32)sh_lut[(pb.y << 8) + pf.y] << 16);
        uint32 w1 = (uint32)sh_lut[(pb.z << 8) + pf.z] | ((uint32)sh_lut[(pb.w << 8) + pf.w] << 16);
        uint2 wv; wv.x = w0; wv.y = w1;
        *(uint2*)&sh_w[0][sn * WS + skq] = wv;
    }
    pb = *(const int4*)(bp + FBK);
    pf = *(const int4*)(fp + FBK);
    __syncthreads();
    const int lane = tid & 63;
    const int wave = tid >> 6;
    const int l16  = lane & 15;
    const int quad = lane >> 4;
    floatx4 acc[2][2];
    const floatx4 zero = {0.f, 0.f, 0.f, 0.f};
    acc[0][0] = zero; acc[0][1] = zero; acc[1][0] = zero; acc[1][1] = zero;
    const int mrow = wave * 32 + l16;
    const float* xrowf = xf + (size_t)mrow * IN_F + quad * 8;
    for (int t = 0; t < NITER; ++t) {
        const int k0 = t * FBK;
        {
            uint32 w0 = (uint32)sh_lut[(pb.x << 8) + pf.x] | ((uint32)sh_lut[(pb.y << 8) + pf.y] << 16);
            uint32 w1 = (uint32)sh_lut[(pb.z << 8) + pf.z] | ((uint32)sh_lut[(pb.w << 8) + pf.w] << 16);
            uint2 wv; wv.x = w0; wv.y = w1;
            *(uint2*)&sh_w[(t + 1) & 1][sn * WS + skq] = wv;
        }
        {
            const int kk = (t + 2 < NITER ? t + 2 : NITER - 1) * FBK;
            pb = *(const int4*)(bp + kk);
            pf = *(const int4*)(fp + kk);
        }
        const ushort_t* wb = sh_w[t & 1];
#pragma unroll
        for (int ks = 0; ks < 4; ++ks) {
            const int kk = k0 + ks * 32;
            short8 b0 = *(const short8*)&wb[l16        * WS + ks * 32 + quad * 8];
            short8 b1 = *(const short8*)&wb[(16 + l16) * WS + ks * 32 + quad * 8];
            short8 a0, a1;
            const float* p0 = xrowf + kk;
            const float* p1 = xrowf + (size_t)16 * IN_F + kk;
            float4 u0 = *(const float4*)p0, u1 = *(const float4*)(p0 + 4);
            float4 v0 = *(const float4*)p1, v1 = *(const float4*)(p1 + 4);
            a0[0] = (short)f2bf(u0.x); a0[1] = (short)f2bf(u0.y);
            a0[2] = (short)f2bf(u0.z); a0[3] = (short)f2bf(u0.w);
            a0[4] = (short)f2bf(u1.x); a0[5] = (short)f2bf(u1.y);
            a0[6] = (short)f2bf(u1.z); a0[7] = (short)f2bf(u1.w);
            a1[0] = (short)f2bf(v0.x); a1[1] = (short)f2bf(v0.y);
            a1[2] = (short)f2bf(v0.z); a1[3] = (short)f2bf(v0.w);
            a1[4] = (short)f2bf(v1.x); a1[5] = (short)f2bf(v1.y);
            a1[6] = (short)f2bf(v1.z); a1[7] = (short)f2bf(v1.w);
            acc[0][0] = __builtin_amdgcn_mfma_f32_16x16x32_bf16(a0, b0, acc[0][0], 0, 0, 0);
            acc[0][1] = __builtin_amdgcn_mfma_f32_16x16x32_bf16(a0, b1, acc[0][1], 0, 0, 0);
            acc[1][0] = __builtin_amdgcn_mfma_f32_16x16x32_bf16(a1, b0, acc[1][0], 0, 0, 0);
            acc[1][1] = __builtin_amdgcn_mfma_f32_16x16x32_bf16(a1, b1, acc[1][1], 0, 0, 0);
        }
        __syncthreads();
    }
#pragma unroll
    for (int nf = 0; nf < 2; ++nf) {
        const int col = n0 + nf * 16 + l16;
        const float sc = scale[col];
#pragma unroll
        for (int f = 0; f < 2; ++f) {
            const int r0 = wave * 32 + f * 16 + quad * 4;
#pragma unroll
            for (int r = 0; r < 4; ++r) {
                out[(size_t)(r0 + r) * OUT_F + col] = acc[f][nf][r] * sc;
            }
        }
    }
}

// ---------------------------------------------------------------------------
extern "C" void kernel_launch(void* const* d_in, const int* in_sizes, int n_in,
                              void* d_out, int out_size, void* d_ws, size_t ws_size,
                              hipStream_t stream) {
    const float* x      = (const float*)d_in[0];
    const int*   bidx   = (const int*)d_in[1];
    const int*   fidx   = (const int*)d_in[2];
    const float* scale  = (const float*)d_in[3];
    const float* lut    = (const float*)d_in[4];
    float*       out    = (float*)d_out;

    const size_t xb_bytes = (size_t)M_TOT * IN_F * sizeof(ushort_t);   // 4 MB

    if (ws_size >= xb_bytes) {
        ushort_t* xbuf = (ushort_t*)d_ws;
        cvt_x_kernel<<<1024, 256, 0, stream>>>(x, xbuf);
        fused_kernel<<<256, 1024, 0, stream>>>(xbuf, bidx, fidx, lut, scale, out);
    } else {
        ghost_kernel<<<OUT_F / NB, 1024, 0, stream>>>(x, bidx, fidx, scale, lut, out);
    }
}